// Round 13
// baseline (144.712 us; speedup 1.0000x reference)
//
#include <hip/hip_runtime.h>
#include <hip/hip_bf16.h>
#include <math.h>

#define D_MODEL   512
#define D_INNER   1024
#define NHEADS    64
#define HEADDIM   16
#define D_STATE   16
#define CONV_DIM  1056
#define D_IN_PROJ 2144
#define CHUNK     256
#define NCHUNK    16
#define BATCH     2
#define SEQ       4096
#define ROWS      (BATCH * SEQ)   // 8192
#define LDZX      2176            // padded bf16 row stride of zx

typedef __bf16    bf16x8 __attribute__((ext_vector_type(8)));
typedef _Float16  f16x8  __attribute__((ext_vector_type(8)));
typedef float     f32x4  __attribute__((ext_vector_type(4)));
typedef float     f32x16 __attribute__((ext_vector_type(16)));
typedef unsigned short u16x8 __attribute__((ext_vector_type(8)));
typedef unsigned int   u32x4 __attribute__((ext_vector_type(4)));

__device__ __forceinline__ float softplusf(float x) {
    return (x > 20.f) ? x : log1pf(expf(x));
}
__device__ __forceinline__ float siluf(float x) {
    return x / (1.f + expf(-x));
}
__device__ __forceinline__ unsigned short f2b(float x) {
    union { __hip_bfloat16 h; unsigned short u; } cv;
    cv.h = __float2bfloat16(x);
    return cv.u;
}
__device__ __forceinline__ float b2f(unsigned short u) {
    union { float f; unsigned int i; } c;
    c.i = (unsigned int)u << 16;
    return c.f;
}
__device__ __forceinline__ void load_lds16(const unsigned short* g, unsigned short* l) {
    __builtin_amdgcn_global_load_lds(
        (const __attribute__((address_space(1))) void*)g,
        (__attribute__((address_space(3))) void*)l,
        16, 0, 0);
}

// ---- fused cast: u (2048 blks) + Win pad (544 blks) + Wout (256 blks) ----
__global__ __launch_bounds__(256) void cast_all(const float* __restrict__ u,
                                                const float* __restrict__ Win,
                                                const float* __restrict__ Wout,
                                                unsigned short* __restrict__ u_bf,
                                                unsigned short* __restrict__ win_bf,
                                                unsigned short* __restrict__ wout_bf) {
    const int bid = blockIdx.x;
    u16x8 o;
    if (bid < 2048) {
        const int i = (bid * 256 + threadIdx.x) * 8;
        float4 a = *(const float4*)(u + i);
        float4 b = *(const float4*)(u + i + 4);
        o[0] = f2b(a.x); o[1] = f2b(a.y); o[2] = f2b(a.z); o[3] = f2b(a.w);
        o[4] = f2b(b.x); o[5] = f2b(b.y); o[6] = f2b(b.z); o[7] = f2b(b.w);
        *(u16x8*)(u_bf + i) = o;
    } else if (bid < 2592) {
        const int i = ((bid - 2048) * 256 + threadIdx.x) * 8;   // npad = 2176*512
        const int n = 2144 * 512;
        if (i + 8 <= n) {
            float4 a = *(const float4*)(Win + i);
            float4 b = *(const float4*)(Win + i + 4);
            o[0] = f2b(a.x); o[1] = f2b(a.y); o[2] = f2b(a.z); o[3] = f2b(a.w);
            o[4] = f2b(b.x); o[5] = f2b(b.y); o[6] = f2b(b.z); o[7] = f2b(b.w);
        } else {
            #pragma unroll
            for (int j = 0; j < 8; ++j) o[j] = (i + j < n) ? f2b(Win[i + j]) : (unsigned short)0;
        }
        *(u16x8*)(win_bf + i) = o;
    } else {
        const int i = ((bid - 2592) * 256 + threadIdx.x) * 8;
        float4 a = *(const float4*)(Wout + i);
        float4 b = *(const float4*)(Wout + i + 4);
        o[0] = f2b(a.x); o[1] = f2b(a.y); o[2] = f2b(a.z); o[3] = f2b(a.w);
        o[4] = f2b(b.x); o[5] = f2b(b.y); o[6] = f2b(b.z); o[7] = f2b(b.w);
        *(u16x8*)(wout_bf + i) = o;
    }
}

// ---- in_proj GEMM: zx[8192,2176(bf16)] = u[8192,512] @ Win[2176,512]^T
// 128x128 tile, BK=64 (8 iters), double-buffered, XCD-swizzled, T2 both-sides
// swizzle (linear LDS dest + inverse-swizzled source + swizzled ds_read),
// stride-128 LDS-transpose bf16 epilogue + fused softplus(dt).
__global__ __launch_bounds__(256) void gemm_in(const unsigned short* __restrict__ A,
                                               const unsigned short* __restrict__ B,
                                               unsigned short* __restrict__ C16,
                                               float* __restrict__ dtsp,
                                               const float* __restrict__ dtb) {
    __shared__ unsigned short smem[32768];   // [2 dbuf][A 8192 | B 8192]; epilogue reuses 16384
    const int t    = threadIdx.x;
    const int wave = t >> 6;
    const int lane = t & 63;
    const int bid  = blockIdx.x;             // grid 1088, %8==0 -> bijective swizzle
    const int swz  = (bid & 7) * 136 + (bid >> 3);
    const int by   = swz / 17;
    const int bx   = swz - by * 17;
    const int bm   = by * 128;
    const int bn   = bx * 128;
    const int wr   = wave >> 1;
    const int wc   = wave & 1;

    const int fr = lane & 15;
    const int kb = (lane >> 4) * 8;

    f32x4 acc[4][4] = {};

    // stage K-tile it (64 cols) into buf it&1: linear LDS dest, inverse-swizzled source.
    // chunk p (16B): row r=p>>3, source slot sl=(p&7)^(r&7)  [read applies same XOR]
    auto stage = [&](int it) {
        const int k0 = it * 64;
        unsigned short* dst = smem + (it & 1) * 16384;
        #pragma unroll
        for (int q = 0; q < 4; ++q) {
            const int p = q * 256 + t;
            const int r = p >> 3;
            const int sl = (p & 7) ^ (r & 7);
            load_lds16(A + (size_t)(bm + r) * 512 + k0 + sl * 8, dst + p * 8);
        }
        #pragma unroll
        for (int q = 0; q < 4; ++q) {
            const int p = q * 256 + t;
            const int r = p >> 3;
            const int sl = (p & 7) ^ (r & 7);
            load_lds16(B + (size_t)(bn + r) * 512 + k0 + sl * 8, dst + 8192 + p * 8);
        }
    };

    stage(0);
    __syncthreads();

    for (int it = 0; it < 8; ++it) {
        if (it + 1 < 8) stage(it + 1);
        const unsigned short* Ab = smem + (it & 1) * 16384;
        const unsigned short* Bb = Ab + 8192;
        #pragma unroll
        for (int kk = 0; kk < 2; ++kk) {
            const int c0 = kk * 32 + kb;
            const int s0 = c0 >> 3;
            bf16x8 af[4], bfr[4];
            #pragma unroll
            for (int m = 0; m < 4; ++m) {
                const int R = wr * 64 + m * 16 + fr;
                af[m] = *reinterpret_cast<const bf16x8*>(&Ab[R * 64 + ((s0 ^ (R & 7)) << 3)]);
            }
            #pragma unroll
            for (int n = 0; n < 4; ++n) {
                const int R = wc * 64 + n * 16 + fr;
                bfr[n] = *reinterpret_cast<const bf16x8*>(&Bb[R * 64 + ((s0 ^ (R & 7)) << 3)]);
            }
            #pragma unroll
            for (int m = 0; m < 4; ++m)
                #pragma unroll
                for (int n = 0; n < 4; ++n)
                    acc[m][n] = __builtin_amdgcn_mfma_f32_16x16x32_bf16(af[m], bfr[n], acc[m][n], 0, 0, 0);
        }
        __syncthreads();
    }

    // fused softplus(dt) side-write: only block-column bn==2048 covers cols 2080..2143
    if (bn == 2048) {
        #pragma unroll
        for (int m = 0; m < 4; ++m) {
            #pragma unroll
            for (int n = 0; n < 4; ++n) {
                const int col = bn + wc * 64 + fr + n * 16;
                if (col >= 2080 && col < 2144) {
                    const int h = col - 2080;
                    const float bias = dtb[h];
                    #pragma unroll
                    for (int j = 0; j < 4; ++j) {
                        const int row = bm + wr * 64 + ((lane >> 4) << 2) + m * 16 + j;
                        dtsp[(size_t)row * 64 + h] = softplusf(acc[m][n][j] + bias);
                    }
                }
            }
        }
    }
    // LDS transpose (stride 128) -> coalesced u16x8 stores
    #pragma unroll
    for (int m = 0; m < 4; ++m) {
        #pragma unroll
        for (int n = 0; n < 4; ++n) {
            const int lcol = wc * 64 + fr + n * 16;
            #pragma unroll
            for (int j = 0; j < 4; ++j) {
                const int lrow = wr * 64 + ((lane >> 4) << 2) + m * 16 + j;
                smem[lrow * 128 + lcol] = f2b(acc[m][n][j]);
            }
        }
    }
    __syncthreads();
    #pragma unroll
    for (int p = 0; p < 8; ++p) {
        const int r = p * 16 + (t >> 4);
        const int cl = (t & 15) * 8;
        u16x8 v = *(const u16x8*)&smem[r * 128 + cl];
        *(u16x8*)(C16 + (size_t)(bm + r) * LDZX + bn + cl) = v;
    }
}

// ---- out_proj GEMM: out[8192,512(f32)] = yn[8192,1024] @ Wout[512,1024]^T
// 128x64 tile, BK=64 (16 iters), double-buffered, T2 both-sides swizzle.
__global__ __launch_bounds__(256) void gemm_out(const unsigned short* __restrict__ A,
                                                const unsigned short* __restrict__ B,
                                                float* __restrict__ C) {
    __shared__ unsigned short smem[24576];   // [2 dbuf][A 8192 | B 4096]
    const int t    = threadIdx.x;
    const int wave = t >> 6;
    const int lane = t & 63;
    const int bm   = blockIdx.y * 128;
    const int bn   = blockIdx.x * 64;
    const int wr   = wave >> 1;
    const int wc   = wave & 1;

    const int fr = lane & 15;
    const int kb = (lane >> 4) * 8;

    f32x4 acc[4][2] = {};

    auto stage = [&](int it) {
        const int k0 = it * 64;
        unsigned short* dst = smem + (it & 1) * 12288;
        #pragma unroll
        for (int q = 0; q < 4; ++q) {
            const int p = q * 256 + t;
            const int r = p >> 3;
            const int sl = (p & 7) ^ (r & 7);
            load_lds16(A + (size_t)(bm + r) * 1024 + k0 + sl * 8, dst + p * 8);
        }
        #pragma unroll
        for (int q = 0; q < 2; ++q) {
            const int p = q * 256 + t;
            const int r = p >> 3;
            const int sl = (p & 7) ^ (r & 7);
            load_lds16(B + (size_t)(bn + r) * 1024 + k0 + sl * 8, dst + 8192 + p * 8);
        }
    };

    stage(0);
    __syncthreads();

    for (int it = 0; it < 16; ++it) {
        if (it + 1 < 16) stage(it + 1);
        const unsigned short* Ab = smem + (it & 1) * 12288;
        const unsigned short* Bb = Ab + 8192;
        #pragma unroll
        for (int kk = 0; kk < 2; ++kk) {
            const int c0 = kk * 32 + kb;
            const int s0 = c0 >> 3;
            bf16x8 af[4], bfr[2];
            #pragma unroll
            for (int m = 0; m < 4; ++m) {
                const int R = wr * 64 + m * 16 + fr;
                af[m] = *reinterpret_cast<const bf16x8*>(&Ab[R * 64 + ((s0 ^ (R & 7)) << 3)]);
            }
            #pragma unroll
            for (int n = 0; n < 2; ++n) {
                const int R = wc * 32 + n * 16 + fr;
                bfr[n] = *reinterpret_cast<const bf16x8*>(&Bb[R * 64 + ((s0 ^ (R & 7)) << 3)]);
            }
            #pragma unroll
            for (int m = 0; m < 4; ++m)
                #pragma unroll
                for (int n = 0; n < 2; ++n)
                    acc[m][n] = __builtin_amdgcn_mfma_f32_16x16x32_bf16(af[m], bfr[n], acc[m][n], 0, 0, 0);
        }
        __syncthreads();
    }

    const int cr0 = bm + wr * 64 + ((lane >> 4) << 2);
    const int cc0 = bn + wc * 32 + fr;
    #pragma unroll
    for (int m = 0; m < 4; ++m)
        #pragma unroll
        for (int n = 0; n < 2; ++n)
            #pragma unroll
            for (int j = 0; j < 4; ++j)
                C[(size_t)(cr0 + m * 16 + j) * 512 + cc0 + n * 16] = acc[m][n][j];
}

// depthwise causal conv(4) + bias + SiLU; 4 rows x 4 channels per thread
__global__ void conv_silu44(const unsigned short* __restrict__ zxb, const float* __restrict__ cw,
                            const float* __restrict__ cb, unsigned short* __restrict__ xcb) {
    int idx = blockIdx.x * blockDim.x + threadIdx.x;
    if (idx >= (ROWS / 4) * (CONV_DIM / 4)) return;
    const int cq  = idx % (CONV_DIM / 4);
    const int blq = idx / (CONV_DIM / 4);
    const int bl0 = blq * 4;
    const int l0  = bl0 % SEQ;
    const int c4  = cq * 4;
    const unsigned short* base = zxb + (size_t)bl0 * LDZX + D_INNER + c4;
    float4 w0 = *(const float4*)(cw + (c4 + 0) * 4);
    float4 w1 = *(const float4*)(cw + (c4 + 1) * 4);
    float4 w2 = *(const float4*)(cw + (c4 + 2) * 4);
    float4 w3 = *(const float4*)(cw + (c4 + 3) * 4);
    float4 bb = *(const float4*)(cb + c4);
    float4 in[7];
    #pragma unroll
    for (int k = 0; k < 7; ++k) {
        const int off = k - 3;
        if (l0 == 0 && k < 3) {
            in[k] = make_float4(0.f, 0.f, 0.f, 0.f);
        } else {
            ushort4 uu = *(const ushort4*)(base + (long)off * LDZX);
            in[k] = make_float4(b2f(uu.x), b2f(uu.y), b2f(uu.z), b2f(uu.w));
        }
    }
    #pragma unroll
    for (int r = 0; r < 4; ++r) {
        ushort4 o;
        o.x = f2b(siluf(bb.x + w0.x * in[r].x + w0.y * in[r + 1].x + w0.z * in[r + 2].x + w0.w * in[r + 3].x));
        o.y = f2b(siluf(bb.y + w1.x * in[r].y + w1.y * in[r + 1].y + w1.z * in[r + 2].y + w1.w * in[r + 3].y));
        o.z = f2b(siluf(bb.z + w2.x * in[r].z + w2.y * in[r + 1].z + w2.z * in[r + 2].z + w2.w * in[r + 3].z));
        o.w = f2b(siluf(bb.w + w3.x * in[r].w + w3.y * in[r + 1].w + w3.z * in[r + 2].w + w3.w * in[r + 3].w));
        *(ushort4*)(xcb + (size_t)(bl0 + r) * CONV_DIM + c4) = o;
    }
}

// per (b, chunk, head) block: 32x32-MFMA intra-chunk Y_diag + end-of-chunk state.
__global__ __launch_bounds__(256, 4) void ssd_chunk(const unsigned short* __restrict__ xcb,
                                                    const float* __restrict__ dtsp,
                                                    const float* __restrict__ A_log,
                                                    unsigned short* __restrict__ ypre16,
                                                    float* __restrict__ states,
                                                    float* __restrict__ csb,
                                                    float* __restrict__ csum) {
    __shared__ _Float16 Bb[256][16];
    __shared__ _Float16 Cb[256][16];       // reused as stpart after Y_diag
    __shared__ _Float16 Xt[16][264];
    __shared__ _Float16 Bt[16][264];
    __shared__ float csL[256];
    __shared__ __align__(16) _Float16 decL[256];
    __shared__ float wsumL[4];

    const int bid = blockIdx.x;
    const int h = bid & 63;
    const int c = (bid >> 6) & 15;
    const int b = bid >> 10;
    const int t = threadIdx.x;
    const int wv = t >> 6;
    const int lane = t & 63;
    const int fr = lane & 15;
    const int hi = lane >> 4;
    const int l31 = lane & 31;
    const int hi5 = lane >> 5;
    const int row = b * SEQ + c * CHUNK + t;

    float Ah  = -__expf(A_log[h]);
    float dtv = dtsp[(size_t)row * NHEADS + h];
    float val = dtv * Ah;
    #pragma unroll
    for (int off = 1; off < 64; off <<= 1) {
        float o = __shfl_up(val, off, 64);
        if (lane >= off) val += o;
    }
    if (lane == 63) wsumL[wv] = val;
    __syncthreads();
    float pre = 0.f, cl = 0.f;
    #pragma unroll
    for (int w2 = 0; w2 < 4; ++w2) {
        float s = wsumL[w2];
        if (w2 < wv) pre += s;
        cl += s;
    }
    float cst = val + pre;
    csL[t] = cst;
    csb[(size_t)bid * 256 + t] = cst;
    if (t == 0) csum[(b * 64 + h) * 16 + c] = cl;
    decL[t] = (_Float16)__expf(cl - cst);

    const unsigned short* xrow = xcb + (size_t)row * CONV_DIM;
    u16x8 braw0 = *(const u16x8*)(xrow + D_INNER);
    u16x8 braw1 = *(const u16x8*)(xrow + D_INNER + 8);
    u16x8 craw0 = *(const u16x8*)(xrow + D_INNER + D_STATE);
    u16x8 craw1 = *(const u16x8*)(xrow + D_INNER + D_STATE + 8);
    u16x8 xraw0 = *(const u16x8*)(xrow + h * HEADDIM);
    u16x8 xraw1 = *(const u16x8*)(xrow + h * HEADDIM + 8);
    float bv[16], cv[16], xv[16];
    #pragma unroll
    for (int n = 0; n < 8; ++n) {
        bv[n] = b2f(braw0[n]); bv[8 + n] = b2f(braw1[n]);
        cv[n] = b2f(craw0[n]); cv[8 + n] = b2f(craw1[n]);
        xv[n] = b2f(xraw0[n]); xv[8 + n] = b2f(xraw1[n]);
    }
    {
        f16x8 pk;
        #pragma unroll
        for (int n = 0; n < 8; ++n) pk[n] = (_Float16)cv[n];
        *(f16x8*)&Cb[t][0] = pk;
        #pragma unroll
        for (int n = 0; n < 8; ++n) pk[n] = (_Float16)cv[8 + n];
        *(f16x8*)&Cb[t][8] = pk;
        #pragma unroll
        for (int n = 0; n < 8; ++n) pk[n] = (_Float16)bv[n];
        *(f16x8*)&Bb[t][0] = pk;
        #pragma unroll
        for (int n = 0; n < 8; ++n) pk[n] = (_Float16)bv[8 + n];
        *(f16x8*)&Bb[t][8] = pk;
    }
    #pragma unroll
    for (int n = 0; n < 16; ++n) {
        Bt[n][t] = (_Float16)bv[n];
        Xt[n][t] = (_Float16)(xv[n] * dtv);
    }
    __syncthreads();

    const int browbase = b * SEQ + c * CHUNK;
    const f32x16 z16 = {};

    #pragma unroll
    for (int halfi = 0; halfi < 2; ++halfi) {
        const int rt = (halfi == 0) ? wv : 7 - wv;
        const int t0 = rt * 32;
        const float cs_t = csL[t0 + l31];
        const f16x8 cfrag = *(const f16x8*)&Cb[t0 + l31][hi5 * 8];
        f32x16 yacc = {};
        for (int sb = 0; sb <= rt; ++sb) {
            const int s0 = sb * 32;
            f16x8 bfrag = *(const f16x8*)&Bb[s0 + l31][hi5 * 8];
            f32x16 sp = __builtin_amdgcn_mfma_f32_32x32x16_f16(bfrag, cfrag, z16, 0, 0, 0);
            const bool diag = (sb == rt);
            unsigned int D[8];
            #pragma unroll
            for (int j = 0; j < 8; ++j) {
                const int q0 = 2 * j;
                const int sr0 = (q0 & 3) + 8 * (q0 >> 2) + 4 * hi5;
                float p0 = sp[q0] * __expf(cs_t - csL[s0 + sr0]);
                float p1 = sp[q0 + 1] * __expf(cs_t - csL[s0 + sr0 + 1]);
                if (diag) {
                    p0 = (sr0 <= l31) ? p0 : 0.f;
                    p1 = (sr0 + 1 <= l31) ? p1 : 0.f;
                }
                D[j] = __builtin_bit_cast(unsigned int, __builtin_amdgcn_cvt_pkrtz(p0, p1));
            }
            unsigned int pD[8];
            #pragma unroll
            for (int j = 0; j < 8; ++j) pD[j] = (unsigned int)__shfl_xor((int)D[j], 32, 64);
            u32x4 fa;
            fa[0] = hi5 ? pD[2] : D[0];
            fa[1] = hi5 ? pD[3] : D[1];
            fa[2] = hi5 ? D[2] : pD[0];
            fa[3] = hi5 ? D[3] : pD[1];
            f16x8 pf0 = __builtin_bit_cast(f16x8, fa);
            f16x8 xf0 = *(const f16x8*)&Xt[fr][s0 + hi5 * 8];
            yacc = __builtin_amdgcn_mfma_f32_32x32x16_f16(pf0, xf0, yacc, 0, 0, 0);
            fa[0] = hi5 ? pD[6] : D[4];
            fa[1] = hi5 ? pD[7] : D[5];
            fa[2] = hi5 ? D[6] : pD[4];
            fa[3] = hi5 ? D[7] : pD[5];
            f16x8 pf1 = __builtin_bit_cast(f16x8, fa);
            f16x8 xf1 = *(const f16x8*)&Xt[fr][s0 + 16 + hi5 * 8];
            yacc = __builtin_amdgcn_mfma_f32_32x32x16_f16(pf1, xf1, yacc, 0, 0, 0);
        }
        if (l31 < 16) {
            #pragma unroll
            for (int q = 0; q < 16; ++q) {
                const int tr = t0 + (q & 3) + 8 * (q >> 2) + 4 * hi5;
                ypre16[(size_t)(browbase + tr) * D_INNER + h * HEADDIM + l31] = f2b(yacc[q]);
            }
        }
    }

    __syncthreads();   // all Cb reads done; safe to alias stpart onto Cb
    float* stpart = (float*)&Cb[0][0];   // [4][16][16] = 4KB
    const int r0w = wv * 64;
    f32x4 stacc = {};
    #pragma unroll
    for (int kt = 0; kt < 2; ++kt) {
        const int sbase = r0w + kt * 32 + hi * 8;
        f16x8 xa = *(const f16x8*)&Xt[fr][sbase];
        f16x8 dd = *(const f16x8*)&decL[sbase];
        xa = xa * dd;
        f16x8 bb2 = *(const f16x8*)&Bt[fr][sbase];
        stacc = __builtin_amdgcn_mfma_f32_16x16x32_f16(xa, bb2, stacc, 0, 0, 0);
    }
    #pragma unroll
    for (int j = 0; j < 4; ++j)
        stpart[wv * 256 + (hi * 4 + j) * 16 + fr] = stacc[j];
    __syncthreads();
    {
        const int p = t >> 4, n = t & 15;
        float st = stpart[0 * 256 + p * 16 + n] + stpart[1 * 256 + p * 16 + n]
                 + stpart[2 * 256 + p * 16 + n] + stpart[3 * 256 + p * 16 + n];
        states[(size_t)bid * 256 + t] = st;
    }
}

// inter-chunk recurrence: prefetch all chunk states, then serial combine in-register
__global__ __launch_bounds__(256) void ssd_rec(const float* __restrict__ states,
                                               const float* __restrict__ csum,
                                               float* __restrict__ prevst) {
    __shared__ float dec[16];
    const int bh = blockIdx.x;
    const int b = bh >> 6, h = bh & 63;
    const int t = threadIdx.x;
    if (t < 16) dec[t] = __expf(csum[bh * 16 + t]);
    float sv[16];
    #pragma unroll
    for (int c = 0; c < NCHUNK; ++c)
        sv[c] = states[((size_t)((b * 16 + c) * 64 + h)) * 256 + t];
    __syncthreads();
    float run = 0.f;
    #pragma unroll
    for (int c = 0; c < NCHUNK; ++c) {
        prevst[((size_t)((b * 16 + c) * 64 + h)) * 256 + t] = run;
        run = run * dec[c] + sv[c];
    }
}

// Fused: Y_off + D skip + SiLU(z) gating + RMSNorm -> bf16 (single-barrier version)
__global__ __launch_bounds__(512, 4) void ssd_off_norm(const unsigned short* __restrict__ xcb,
                                                       const unsigned short* __restrict__ zxb,
                                                       const unsigned short* __restrict__ ypre16,
                                                       const float* __restrict__ prevst,
                                                       const float* __restrict__ csb,
                                                       const float* __restrict__ Dskip,
                                                       const float* __restrict__ normw,
                                                       unsigned short* __restrict__ yout) {
    __shared__ float Cs[16][16];
    __shared__ float csS[64][16];
    __shared__ float nw[1024];
    __shared__ float Dn[64];
    __shared__ float red[16][8];

    const int blk = blockIdx.x;
    const int bc = blk >> 4;          // b*16 + c
    const int rb = blk & 15;
    const int r0 = rb * 16;
    const int b = bc >> 4, c = bc & 15;
    const int brow0 = b * SEQ + c * CHUNK;
    const int t = threadIdx.x;
    const int ch0 = t * 2;
    const int h = ch0 >> 4;
    const int p0 = ch0 & 15;
    const int wv = t >> 6;
    const int lane = t & 63;

    if (t < 256) *(float4*)&nw[t * 4] = *(const float4*)(normw + t * 4);
    else if (t < 320) Dn[t - 256] = Dskip[t - 256];
    if (t < 64) {
        int r = t >> 2, n4 = (t & 3) * 4;
        ushort4 uu = *(const ushort4*)(xcb + (size_t)(brow0 + r0 + r) * CONV_DIM
                                       + D_INNER + D_STATE + n4);
        Cs[r][n4 + 0] = b2f(uu.x); Cs[r][n4 + 1] = b2f(uu.y);
        Cs[r][n4 + 2] = b2f(uu.z); Cs[r][n4 + 3] = b2f(uu.w);
    }
    #pragma unroll
    for (int i = t; i < 1024; i += 512) {
        int r = i & 15, hh = i >> 4;
        csS[hh][r] = csb[(size_t)(bc * 64 + hh) * 256 + r0 + r];
    }

    float ps[2][16];
    {
        const float* pbase = prevst + (size_t)(bc * 64 + h) * 256 + p0 * 16;
        #pragma unroll
        for (int n4 = 0; n4 < 16; n4 += 4) {
            *(float4*)&ps[0][n4] = *(const float4*)(pbase + n4);
            *(float4*)&ps[1][n4] = *(const float4*)(pbase + 16 + n4);
        }
    }
    __syncthreads();

    const float d = Dn[h];
    const float nw0 = nw[ch0], nw1 = nw[ch0 + 1];

    float g0r[16], g1r[16];
    #pragma unroll
    for (int r = 0; r < 16; ++r) {
        const size_t grow = (size_t)(brow0 + r0 + r);
        ushort2 yu = *(const ushort2*)(ypre16 + grow * D_INNER + ch0);
        ushort2 xu = *(const ushort2*)(xcb + grow * CONV_DIM + ch0);
        ushort2 zu = *(const ushort2*)(zxb + grow * LDZX + ch0);
        float sdo = __expf(csS[h][r]);
        float off0 = 0.f, off1 = 0.f;
        #pragma unroll
        for (int n = 0; n < 16; ++n) {
            float cn = Cs[r][n];
            off0 += cn * ps[0][n];
            off1 += cn * ps[1][n];
        }
        float g0 = (b2f(yu.x) + sdo * off0 + b2f(xu.x) * d) * siluf(b2f(zu.x));
        float g1 = (b2f(yu.y) + sdo * off1 + b2f(xu.y) * d) * siluf(b2f(zu.y));
        g0r[r] = g0; g1r[r] = g1;
        float s = g0 * g0 + g1 * g1;
        #pragma unroll
        for (int o = 32; o > 0; o >>= 1) s += __shfl_down(s, o, 64);
        if (lane == 0) red[r][wv] = s;
    }
    __syncthreads();
    #pragma unroll
    for (int r = 0; r < 16; ++r) {
        const size_t grow = (size_t)(brow0 + r0 + r);
        float tot = 0.f;
        #pragma unroll
        for (int w2 = 0; w2 < 8; ++w2) tot += red[r][w2];
        float rstd = rsqrtf(tot * (1.f / (float)D_INNER) + 1e-5f);
        ushort2 o2;
        o2.x = f2b(g0r[r] * rstd * nw0);
        o2.y = f2b(g1r[r] * rstd * nw1);
        *(ushort2*)(yout + grow * D_INNER + ch0) = o2;
    }
}

extern "C" void kernel_launch(void* const* d_in, const int* in_sizes, int n_in,
                              void* d_out, int out_size, void* d_ws, size_t ws_size,
                              hipStream_t stream) {
    const float* u     = (const float*)d_in[0];
    const float* Win   = (const float*)d_in[1];
    const float* cw    = (const float*)d_in[2];
    const float* cb    = (const float*)d_in[3];
    const float* dtb   = (const float*)d_in[4];
    const float* Alog  = (const float*)d_in[5];
    const float* Dsk   = (const float*)d_in[6];
    const float* normw = (const float*)d_in[7];
    const float* Wout  = (const float*)d_in[8];
    float* out = (float*)d_out;

    float* ws = (float*)d_ws;
    unsigned short* zxb = (unsigned short*)ws;             // 8192*2176 bf16 = 8,912,896 f32
    float* dtsp   = ws + 8912896;                          // 524288
    float* csb    = dtsp + 524288;                         // 524288
    float* st     = csb + 524288;                          // 524288
    float* pst    = st + 524288;                           // 524288
    float* csum   = pst + 524288;                          // 2048
    unsigned short* ypre16 = (unsigned short*)(csum + 2048);              // 8192*1024 bf16
    unsigned short* xcb    = (unsigned short*)((float*)ypre16 + 4194304); // 8,650,752 bf16
    unsigned short* yn_bf  = (unsigned short*)((float*)xcb + 4325376);    // 8192*1024 bf16
    unsigned short* u_bf   = (unsigned short*)((float*)yn_bf + 2097152);  // 8192*512 bf16
    unsigned short* win_bf  = (unsigned short*)((float*)u_bf + 2097152);  // 2176*512 bf16
    unsigned short* wout_bf = (unsigned short*)((float*)win_bf + 557056); // 512*1024 bf16

    cast_all<<<2848, 256, 0, stream>>>(u, Win, Wout, u_bf, win_bf, wout_bf);

    gemm_in<<<1088, 256, 0, stream>>>(u_bf, win_bf, zxb, dtsp, dtb);

    conv_silu44<<<(ROWS / 4) * (CONV_DIM / 4) / 256, 256, 0, stream>>>(zxb, cw, cb, xcb);
    ssd_chunk<<<BATCH * NCHUNK * NHEADS, 256, 0, stream>>>(xcb, dtsp, Alog, ypre16, st, csb, csum);
    ssd_rec<<<BATCH * NHEADS, 256, 0, stream>>>(st, csum, pst);
    ssd_off_norm<<<512, 512, 0, stream>>>(xcb, zxb, ypre16, pst, csb, Dsk, normw, yn_bf);

    gemm_out<<<dim3(8, 64), 256, 0, stream>>>(yn_bf, wout_bf, out);
}

// Round 14
// 142.450 us; speedup vs baseline: 1.0159x; 1.0159x over previous
//
#include <hip/hip_runtime.h>
#include <hip/hip_bf16.h>
#include <math.h>

#define D_MODEL   512
#define D_INNER   1024
#define NHEADS    64
#define HEADDIM   16
#define D_STATE   16
#define CONV_DIM  1056
#define D_IN_PROJ 2144
#define CHUNK     256
#define NCHUNK    16
#define BATCH     2
#define SEQ       4096
#define ROWS      (BATCH * SEQ)   // 8192
#define LDZX      2176            // padded bf16 row stride of zx

typedef __bf16    bf16x8 __attribute__((ext_vector_type(8)));
typedef _Float16  f16x8  __attribute__((ext_vector_type(8)));
typedef float     f32x4  __attribute__((ext_vector_type(4)));
typedef float     f32x16 __attribute__((ext_vector_type(16)));
typedef unsigned short u16x8 __attribute__((ext_vector_type(8)));
typedef unsigned int   u32x4 __attribute__((ext_vector_type(4)));

__device__ __forceinline__ float softplusf(float x) {
    return (x > 20.f) ? x : log1pf(expf(x));
}
__device__ __forceinline__ float siluf(float x) {
    return x / (1.f + expf(-x));
}
__device__ __forceinline__ unsigned short f2b(float x) {
    union { __hip_bfloat16 h; unsigned short u; } cv;
    cv.h = __float2bfloat16(x);
    return cv.u;
}
__device__ __forceinline__ float b2f(unsigned short u) {
    union { float f; unsigned int i; } c;
    c.i = (unsigned int)u << 16;
    return c.f;
}
__device__ __forceinline__ void load_lds16(const unsigned short* g, unsigned short* l) {
    __builtin_amdgcn_global_load_lds(
        (const __attribute__((address_space(1))) void*)g,
        (__attribute__((address_space(3))) void*)l,
        16, 0, 0);
}

// ---- fused cast: u (2048 blks) + Win pad (544 blks) + Wout (256 blks) ----
__global__ __launch_bounds__(256) void cast_all(const float* __restrict__ u,
                                                const float* __restrict__ Win,
                                                const float* __restrict__ Wout,
                                                unsigned short* __restrict__ u_bf,
                                                unsigned short* __restrict__ win_bf,
                                                unsigned short* __restrict__ wout_bf) {
    const int bid = blockIdx.x;
    u16x8 o;
    if (bid < 2048) {
        const int i = (bid * 256 + threadIdx.x) * 8;
        float4 a = *(const float4*)(u + i);
        float4 b = *(const float4*)(u + i + 4);
        o[0] = f2b(a.x); o[1] = f2b(a.y); o[2] = f2b(a.z); o[3] = f2b(a.w);
        o[4] = f2b(b.x); o[5] = f2b(b.y); o[6] = f2b(b.z); o[7] = f2b(b.w);
        *(u16x8*)(u_bf + i) = o;
    } else if (bid < 2592) {
        const int i = ((bid - 2048) * 256 + threadIdx.x) * 8;   // npad = 2176*512
        const int n = 2144 * 512;
        if (i + 8 <= n) {
            float4 a = *(const float4*)(Win + i);
            float4 b = *(const float4*)(Win + i + 4);
            o[0] = f2b(a.x); o[1] = f2b(a.y); o[2] = f2b(a.z); o[3] = f2b(a.w);
            o[4] = f2b(b.x); o[5] = f2b(b.y); o[6] = f2b(b.z); o[7] = f2b(b.w);
        } else {
            #pragma unroll
            for (int j = 0; j < 8; ++j) o[j] = (i + j < n) ? f2b(Win[i + j]) : (unsigned short)0;
        }
        *(u16x8*)(win_bf + i) = o;
    } else {
        const int i = ((bid - 2592) * 256 + threadIdx.x) * 8;
        float4 a = *(const float4*)(Wout + i);
        float4 b = *(const float4*)(Wout + i + 4);
        o[0] = f2b(a.x); o[1] = f2b(a.y); o[2] = f2b(a.z); o[3] = f2b(a.w);
        o[4] = f2b(b.x); o[5] = f2b(b.y); o[6] = f2b(b.z); o[7] = f2b(b.w);
        *(u16x8*)(wout_bf + i) = o;
    }
}

// ---- in_proj GEMM: zx[8192,2176(bf16)] = u[8192,512] @ Win[2176,512]^T
// 128x64 tile (4 waves 2x2, 64x32 each), BK=64 (8 iters), double-buffered (48KB ->
// 3 blocks/CU), XCD-swizzled, T2 both-sides swizzle, stride-72 transpose epilogue,
// fused softplus(dt).
__global__ __launch_bounds__(256) void gemm_in(const unsigned short* __restrict__ A,
                                               const unsigned short* __restrict__ B,
                                               unsigned short* __restrict__ C16,
                                               float* __restrict__ dtsp,
                                               const float* __restrict__ dtb) {
    __shared__ unsigned short smem[24576];   // 2 x (A 8192 | B 4096); epilogue 128x72
    const int t    = threadIdx.x;
    const int wave = t >> 6;
    const int lane = t & 63;
    const int bid  = blockIdx.x;             // grid 2176 = 64x34, %8==0 -> bijective swizzle
    const int swz  = (bid & 7) * 272 + (bid >> 3);
    const int by   = swz / 34;
    const int bx   = swz - by * 34;
    const int bm   = by * 128;
    const int bn   = bx * 64;
    const int wr   = wave >> 1;
    const int wc   = wave & 1;

    const int fr = lane & 15;
    const int kb = (lane >> 4) * 8;

    f32x4 acc[4][2] = {};

    // stage K-tile it (64 cols): linear LDS dest, inverse-swizzled global source.
    auto stage = [&](int it) {
        const int k0 = it * 64;
        unsigned short* dst = smem + (it & 1) * 12288;
        #pragma unroll
        for (int q = 0; q < 4; ++q) {
            const int p = q * 256 + t;
            const int r = p >> 3;
            const int sl = (p & 7) ^ (r & 7);
            load_lds16(A + (size_t)(bm + r) * 512 + k0 + sl * 8, dst + p * 8);
        }
        #pragma unroll
        for (int q = 0; q < 2; ++q) {
            const int p = q * 256 + t;
            const int r = p >> 3;
            const int sl = (p & 7) ^ (r & 7);
            load_lds16(B + (size_t)(bn + r) * 512 + k0 + sl * 8, dst + 8192 + p * 8);
        }
    };

    stage(0);
    __syncthreads();

    for (int it = 0; it < 8; ++it) {
        if (it + 1 < 8) stage(it + 1);
        const unsigned short* Ab = smem + (it & 1) * 12288;
        const unsigned short* Bb = Ab + 8192;
        #pragma unroll
        for (int kk = 0; kk < 2; ++kk) {
            const int s0 = (kk * 32 + kb) >> 3;
            bf16x8 af[4], bfr[2];
            #pragma unroll
            for (int m = 0; m < 4; ++m) {
                const int R = wr * 64 + m * 16 + fr;
                af[m] = *reinterpret_cast<const bf16x8*>(&Ab[R * 64 + ((s0 ^ (R & 7)) << 3)]);
            }
            #pragma unroll
            for (int n = 0; n < 2; ++n) {
                const int R = wc * 32 + n * 16 + fr;
                bfr[n] = *reinterpret_cast<const bf16x8*>(&Bb[R * 64 + ((s0 ^ (R & 7)) << 3)]);
            }
            #pragma unroll
            for (int m = 0; m < 4; ++m)
                #pragma unroll
                for (int n = 0; n < 2; ++n)
                    acc[m][n] = __builtin_amdgcn_mfma_f32_16x16x32_bf16(af[m], bfr[n], acc[m][n], 0, 0, 0);
        }
        __syncthreads();
    }

    // fused softplus(dt) side-write: cols 2080..2143 live in bn==2048 / bn==2112
    if (bn == 2048 || bn == 2112) {
        #pragma unroll
        for (int m = 0; m < 4; ++m) {
            #pragma unroll
            for (int n = 0; n < 2; ++n) {
                const int col = bn + wc * 32 + fr + n * 16;
                if (col >= 2080 && col < 2144) {
                    const int h = col - 2080;
                    const float bias = dtb[h];
                    #pragma unroll
                    for (int j = 0; j < 4; ++j) {
                        const int row = bm + wr * 64 + ((lane >> 4) << 2) + m * 16 + j;
                        dtsp[(size_t)row * 64 + h] = softplusf(acc[m][n][j] + bias);
                    }
                }
            }
        }
    }
    // LDS transpose (stride 72: 16B-aligned rows, diagonal bank spread) -> u16x8 stores
    #pragma unroll
    for (int m = 0; m < 4; ++m) {
        #pragma unroll
        for (int n = 0; n < 2; ++n) {
            const int lcol = wc * 32 + fr + n * 16;
            #pragma unroll
            for (int j = 0; j < 4; ++j) {
                const int lrow = wr * 64 + ((lane >> 4) << 2) + m * 16 + j;
                smem[lrow * 72 + lcol] = f2b(acc[m][n][j]);
            }
        }
    }
    __syncthreads();
    #pragma unroll
    for (int q = 0; q < 4; ++q) {
        const int idx = q * 256 + t;
        const int r = idx >> 3;
        const int cl = (idx & 7) * 8;
        u16x8 v = *(const u16x8*)&smem[r * 72 + cl];
        *(u16x8*)(C16 + (size_t)(bm + r) * LDZX + bn + cl) = v;
    }
}

// ---- out_proj GEMM: out[8192,512(f32)] = yn[8192,1024] @ Wout[512,1024]^T
// (round-12 exact: 128x64 tile, BK=32, double-buffered, no swizzle)
__global__ __launch_bounds__(256) void gemm_out(const unsigned short* __restrict__ A,
                                                const unsigned short* __restrict__ B,
                                                float* __restrict__ C) {
    __shared__ unsigned short smem[12288];   // A dbuf [0,8192), B dbuf [8192,12288)
    const int t    = threadIdx.x;
    const int wave = t >> 6;
    const int lane = t & 63;
    const int bm   = blockIdx.y * 128;
    const int bn   = blockIdx.x * 64;
    const int wr   = wave >> 1;
    const int wc   = wave & 1;

    const int srow = wave * 16 + (lane >> 2);
    const int scol = (lane & 3) * 8;
    const unsigned short* ga0 = A + (size_t)(bm + srow) * 1024 + scol;
    const unsigned short* ga1 = A + (size_t)(bm + 64 + srow) * 1024 + scol;
    const unsigned short* gb0 = B + (size_t)(bn + srow) * 1024 + scol;

    const int fr = lane & 15;
    const int kb = (lane >> 4) * 8;

    f32x4 acc[4][2] = {};

    load_lds16(ga0, smem + wave * 512);
    load_lds16(ga1, smem + 2048 + wave * 512);
    load_lds16(gb0, smem + 8192 + wave * 512);
    __syncthreads();

    int cur = 0;
    for (int it = 0; it < 32; ++it) {
        if (it + 1 < 32) {
            const int k0 = (it + 1) * 32;
            const int nb = cur ^ 1;
            load_lds16(ga0 + k0, smem + nb * 4096 + wave * 512);
            load_lds16(ga1 + k0, smem + nb * 4096 + 2048 + wave * 512);
            load_lds16(gb0 + k0, smem + 8192 + nb * 2048 + wave * 512);
        }
        const unsigned short* Ab = smem + cur * 4096;
        const unsigned short* Bb = smem + 8192 + cur * 2048;
        bf16x8 af[4], bfr[2];
        #pragma unroll
        for (int m = 0; m < 4; ++m)
            af[m] = *reinterpret_cast<const bf16x8*>(&Ab[(wr * 64 + m * 16 + fr) * 32 + kb]);
        #pragma unroll
        for (int n = 0; n < 2; ++n)
            bfr[n] = *reinterpret_cast<const bf16x8*>(&Bb[(wc * 32 + n * 16 + fr) * 32 + kb]);
        #pragma unroll
        for (int m = 0; m < 4; ++m)
            #pragma unroll
            for (int n = 0; n < 2; ++n)
                acc[m][n] = __builtin_amdgcn_mfma_f32_16x16x32_bf16(af[m], bfr[n], acc[m][n], 0, 0, 0);
        __syncthreads();
        cur ^= 1;
    }

    const int cr0 = bm + wr * 64 + ((lane >> 4) << 2);
    const int cc0 = bn + wc * 32 + fr;
    #pragma unroll
    for (int m = 0; m < 4; ++m)
        #pragma unroll
        for (int n = 0; n < 2; ++n)
            #pragma unroll
            for (int j = 0; j < 4; ++j)
                C[(size_t)(cr0 + m * 16 + j) * 512 + cc0 + n * 16] = acc[m][n][j];
}

// depthwise causal conv(4) + bias + SiLU; 4 rows x 4 channels per thread
__global__ void conv_silu44(const unsigned short* __restrict__ zxb, const float* __restrict__ cw,
                            const float* __restrict__ cb, unsigned short* __restrict__ xcb) {
    int idx = blockIdx.x * blockDim.x + threadIdx.x;
    if (idx >= (ROWS / 4) * (CONV_DIM / 4)) return;
    const int cq  = idx % (CONV_DIM / 4);
    const int blq = idx / (CONV_DIM / 4);
    const int bl0 = blq * 4;
    const int l0  = bl0 % SEQ;
    const int c4  = cq * 4;
    const unsigned short* base = zxb + (size_t)bl0 * LDZX + D_INNER + c4;
    float4 w0 = *(const float4*)(cw + (c4 + 0) * 4);
    float4 w1 = *(const float4*)(cw + (c4 + 1) * 4);
    float4 w2 = *(const float4*)(cw + (c4 + 2) * 4);
    float4 w3 = *(const float4*)(cw + (c4 + 3) * 4);
    float4 bb = *(const float4*)(cb + c4);
    float4 in[7];
    #pragma unroll
    for (int k = 0; k < 7; ++k) {
        const int off = k - 3;
        if (l0 == 0 && k < 3) {
            in[k] = make_float4(0.f, 0.f, 0.f, 0.f);
        } else {
            ushort4 uu = *(const ushort4*)(base + (long)off * LDZX);
            in[k] = make_float4(b2f(uu.x), b2f(uu.y), b2f(uu.z), b2f(uu.w));
        }
    }
    #pragma unroll
    for (int r = 0; r < 4; ++r) {
        ushort4 o;
        o.x = f2b(siluf(bb.x + w0.x * in[r].x + w0.y * in[r + 1].x + w0.z * in[r + 2].x + w0.w * in[r + 3].x));
        o.y = f2b(siluf(bb.y + w1.x * in[r].y + w1.y * in[r + 1].y + w1.z * in[r + 2].y + w1.w * in[r + 3].y));
        o.z = f2b(siluf(bb.z + w2.x * in[r].z + w2.y * in[r + 1].z + w2.z * in[r + 2].z + w2.w * in[r + 3].z));
        o.w = f2b(siluf(bb.w + w3.x * in[r].w + w3.y * in[r + 1].w + w3.z * in[r + 2].w + w3.w * in[r + 3].w));
        *(ushort4*)(xcb + (size_t)(bl0 + r) * CONV_DIM + c4) = o;
    }
}

// per (b, chunk, head) block: 32x32-MFMA intra-chunk Y_diag + end-of-chunk state.
__global__ __launch_bounds__(256, 4) void ssd_chunk(const unsigned short* __restrict__ xcb,
                                                    const float* __restrict__ dtsp,
                                                    const float* __restrict__ A_log,
                                                    unsigned short* __restrict__ ypre16,
                                                    float* __restrict__ states,
                                                    float* __restrict__ csb,
                                                    float* __restrict__ csum) {
    __shared__ _Float16 Bb[256][16];
    __shared__ _Float16 Cb[256][16];       // reused as stpart after Y_diag
    __shared__ _Float16 Xt[16][264];
    __shared__ _Float16 Bt[16][264];
    __shared__ float csL[256];
    __shared__ __align__(16) _Float16 decL[256];
    __shared__ float wsumL[4];

    const int bid = blockIdx.x;
    const int h = bid & 63;
    const int c = (bid >> 6) & 15;
    const int b = bid >> 10;
    const int t = threadIdx.x;
    const int wv = t >> 6;
    const int lane = t & 63;
    const int fr = lane & 15;
    const int hi = lane >> 4;
    const int l31 = lane & 31;
    const int hi5 = lane >> 5;
    const int row = b * SEQ + c * CHUNK + t;

    float Ah  = -__expf(A_log[h]);
    float dtv = dtsp[(size_t)row * NHEADS + h];
    float val = dtv * Ah;
    #pragma unroll
    for (int off = 1; off < 64; off <<= 1) {
        float o = __shfl_up(val, off, 64);
        if (lane >= off) val += o;
    }
    if (lane == 63) wsumL[wv] = val;
    __syncthreads();
    float pre = 0.f, cl = 0.f;
    #pragma unroll
    for (int w2 = 0; w2 < 4; ++w2) {
        float s = wsumL[w2];
        if (w2 < wv) pre += s;
        cl += s;
    }
    float cst = val + pre;
    csL[t] = cst;
    csb[(size_t)bid * 256 + t] = cst;
    if (t == 0) csum[(b * 64 + h) * 16 + c] = cl;
    decL[t] = (_Float16)__expf(cl - cst);

    const unsigned short* xrow = xcb + (size_t)row * CONV_DIM;
    u16x8 braw0 = *(const u16x8*)(xrow + D_INNER);
    u16x8 braw1 = *(const u16x8*)(xrow + D_INNER + 8);
    u16x8 craw0 = *(const u16x8*)(xrow + D_INNER + D_STATE);
    u16x8 craw1 = *(const u16x8*)(xrow + D_INNER + D_STATE + 8);
    u16x8 xraw0 = *(const u16x8*)(xrow + h * HEADDIM);
    u16x8 xraw1 = *(const u16x8*)(xrow + h * HEADDIM + 8);
    float bv[16], cv[16], xv[16];
    #pragma unroll
    for (int n = 0; n < 8; ++n) {
        bv[n] = b2f(braw0[n]); bv[8 + n] = b2f(braw1[n]);
        cv[n] = b2f(craw0[n]); cv[8 + n] = b2f(craw1[n]);
        xv[n] = b2f(xraw0[n]); xv[8 + n] = b2f(xraw1[n]);
    }
    {
        f16x8 pk;
        #pragma unroll
        for (int n = 0; n < 8; ++n) pk[n] = (_Float16)cv[n];
        *(f16x8*)&Cb[t][0] = pk;
        #pragma unroll
        for (int n = 0; n < 8; ++n) pk[n] = (_Float16)cv[8 + n];
        *(f16x8*)&Cb[t][8] = pk;
        #pragma unroll
        for (int n = 0; n < 8; ++n) pk[n] = (_Float16)bv[n];
        *(f16x8*)&Bb[t][0] = pk;
        #pragma unroll
        for (int n = 0; n < 8; ++n) pk[n] = (_Float16)bv[8 + n];
        *(f16x8*)&Bb[t][8] = pk;
    }
    #pragma unroll
    for (int n = 0; n < 16; ++n) {
        Bt[n][t] = (_Float16)bv[n];
        Xt[n][t] = (_Float16)(xv[n] * dtv);
    }
    __syncthreads();

    const int browbase = b * SEQ + c * CHUNK;
    const f32x16 z16 = {};

    #pragma unroll
    for (int halfi = 0; halfi < 2; ++halfi) {
        const int rt = (halfi == 0) ? wv : 7 - wv;
        const int t0 = rt * 32;
        const float cs_t = csL[t0 + l31];
        const f16x8 cfrag = *(const f16x8*)&Cb[t0 + l31][hi5 * 8];
        f32x16 yacc = {};
        for (int sb = 0; sb <= rt; ++sb) {
            const int s0 = sb * 32;
            f16x8 bfrag = *(const f16x8*)&Bb[s0 + l31][hi5 * 8];
            f32x16 sp = __builtin_amdgcn_mfma_f32_32x32x16_f16(bfrag, cfrag, z16, 0, 0, 0);
            const bool diag = (sb == rt);
            unsigned int D[8];
            #pragma unroll
            for (int j = 0; j < 8; ++j) {
                const int q0 = 2 * j;
                const int sr0 = (q0 & 3) + 8 * (q0 >> 2) + 4 * hi5;
                float p0 = sp[q0] * __expf(cs_t - csL[s0 + sr0]);
                float p1 = sp[q0 + 1] * __expf(cs_t - csL[s0 + sr0 + 1]);
                if (diag) {
                    p0 = (sr0 <= l31) ? p0 : 0.f;
                    p1 = (sr0 + 1 <= l31) ? p1 : 0.f;
                }
                D[j] = __builtin_bit_cast(unsigned int, __builtin_amdgcn_cvt_pkrtz(p0, p1));
            }
            unsigned int pD[8];
            #pragma unroll
            for (int j = 0; j < 8; ++j) pD[j] = (unsigned int)__shfl_xor((int)D[j], 32, 64);
            u32x4 fa;
            fa[0] = hi5 ? pD[2] : D[0];
            fa[1] = hi5 ? pD[3] : D[1];
            fa[2] = hi5 ? D[2] : pD[0];
            fa[3] = hi5 ? D[3] : pD[1];
            f16x8 pf0 = __builtin_bit_cast(f16x8, fa);
            f16x8 xf0 = *(const f16x8*)&Xt[fr][s0 + hi5 * 8];
            yacc = __builtin_amdgcn_mfma_f32_32x32x16_f16(pf0, xf0, yacc, 0, 0, 0);
            fa[0] = hi5 ? pD[6] : D[4];
            fa[1] = hi5 ? pD[7] : D[5];
            fa[2] = hi5 ? D[6] : pD[4];
            fa[3] = hi5 ? D[7] : pD[5];
            f16x8 pf1 = __builtin_bit_cast(f16x8, fa);
            f16x8 xf1 = *(const f16x8*)&Xt[fr][s0 + 16 + hi5 * 8];
            yacc = __builtin_amdgcn_mfma_f32_32x32x16_f16(pf1, xf1, yacc, 0, 0, 0);
        }
        if (l31 < 16) {
            #pragma unroll
            for (int q = 0; q < 16; ++q) {
                const int tr = t0 + (q & 3) + 8 * (q >> 2) + 4 * hi5;
                ypre16[(size_t)(browbase + tr) * D_INNER + h * HEADDIM + l31] = f2b(yacc[q]);
            }
        }
    }

    __syncthreads();   // all Cb reads done; safe to alias stpart onto Cb
    float* stpart = (float*)&Cb[0][0];   // [4][16][16] = 4KB
    const int r0w = wv * 64;
    f32x4 stacc = {};
    #pragma unroll
    for (int kt = 0; kt < 2; ++kt) {
        const int sbase = r0w + kt * 32 + hi * 8;
        f16x8 xa = *(const f16x8*)&Xt[fr][sbase];
        f16x8 dd = *(const f16x8*)&decL[sbase];
        xa = xa * dd;
        f16x8 bb2 = *(const f16x8*)&Bt[fr][sbase];
        stacc = __builtin_amdgcn_mfma_f32_16x16x32_f16(xa, bb2, stacc, 0, 0, 0);
    }
    #pragma unroll
    for (int j = 0; j < 4; ++j)
        stpart[wv * 256 + (hi * 4 + j) * 16 + fr] = stacc[j];
    __syncthreads();
    {
        const int p = t >> 4, n = t & 15;
        float st = stpart[0 * 256 + p * 16 + n] + stpart[1 * 256 + p * 16 + n]
                 + stpart[2 * 256 + p * 16 + n] + stpart[3 * 256 + p * 16 + n];
        states[(size_t)bid * 256 + t] = st;
    }
}

// inter-chunk recurrence: prefetch all chunk states, then serial combine in-register
__global__ __launch_bounds__(256) void ssd_rec(const float* __restrict__ states,
                                               const float* __restrict__ csum,
                                               float* __restrict__ prevst) {
    __shared__ float dec[16];
    const int bh = blockIdx.x;
    const int b = bh >> 6, h = bh & 63;
    const int t = threadIdx.x;
    if (t < 16) dec[t] = __expf(csum[bh * 16 + t]);
    float sv[16];
    #pragma unroll
    for (int c = 0; c < NCHUNK; ++c)
        sv[c] = states[((size_t)((b * 16 + c) * 64 + h)) * 256 + t];
    __syncthreads();
    float run = 0.f;
    #pragma unroll
    for (int c = 0; c < NCHUNK; ++c) {
        prevst[((size_t)((b * 16 + c) * 64 + h)) * 256 + t] = run;
        run = run * dec[c] + sv[c];
    }
}

// Fused: Y_off + D skip + SiLU(z) gating + RMSNorm -> bf16 (single-barrier version)
__global__ __launch_bounds__(512, 4) void ssd_off_norm(const unsigned short* __restrict__ xcb,
                                                       const unsigned short* __restrict__ zxb,
                                                       const unsigned short* __restrict__ ypre16,
                                                       const float* __restrict__ prevst,
                                                       const float* __restrict__ csb,
                                                       const float* __restrict__ Dskip,
                                                       const float* __restrict__ normw,
                                                       unsigned short* __restrict__ yout) {
    __shared__ float Cs[16][16];
    __shared__ float csS[64][16];
    __shared__ float nw[1024];
    __shared__ float Dn[64];
    __shared__ float red[16][8];

    const int blk = blockIdx.x;
    const int bc = blk >> 4;          // b*16 + c
    const int rb = blk & 15;
    const int r0 = rb * 16;
    const int b = bc >> 4, c = bc & 15;
    const int brow0 = b * SEQ + c * CHUNK;
    const int t = threadIdx.x;
    const int ch0 = t * 2;
    const int h = ch0 >> 4;
    const int p0 = ch0 & 15;
    const int wv = t >> 6;
    const int lane = t & 63;

    if (t < 256) *(float4*)&nw[t * 4] = *(const float4*)(normw + t * 4);
    else if (t < 320) Dn[t - 256] = Dskip[t - 256];
    if (t < 64) {
        int r = t >> 2, n4 = (t & 3) * 4;
        ushort4 uu = *(const ushort4*)(xcb + (size_t)(brow0 + r0 + r) * CONV_DIM
                                       + D_INNER + D_STATE + n4);
        Cs[r][n4 + 0] = b2f(uu.x); Cs[r][n4 + 1] = b2f(uu.y);
        Cs[r][n4 + 2] = b2f(uu.z); Cs[r][n4 + 3] = b2f(uu.w);
    }
    #pragma unroll
    for (int i = t; i < 1024; i += 512) {
        int r = i & 15, hh = i >> 4;
        csS[hh][r] = csb[(size_t)(bc * 64 + hh) * 256 + r0 + r];
    }

    float ps[2][16];
    {
        const float* pbase = prevst + (size_t)(bc * 64 + h) * 256 + p0 * 16;
        #pragma unroll
        for (int n4 = 0; n4 < 16; n4 += 4) {
            *(float4*)&ps[0][n4] = *(const float4*)(pbase + n4);
            *(float4*)&ps[1][n4] = *(const float4*)(pbase + 16 + n4);
        }
    }
    __syncthreads();

    const float d = Dn[h];
    const float nw0 = nw[ch0], nw1 = nw[ch0 + 1];

    float g0r[16], g1r[16];
    #pragma unroll
    for (int r = 0; r < 16; ++r) {
        const size_t grow = (size_t)(brow0 + r0 + r);
        ushort2 yu = *(const ushort2*)(ypre16 + grow * D_INNER + ch0);
        ushort2 xu = *(const ushort2*)(xcb + grow * CONV_DIM + ch0);
        ushort2 zu = *(const ushort2*)(zxb + grow * LDZX + ch0);
        float sdo = __expf(csS[h][r]);
        float off0 = 0.f, off1 = 0.f;
        #pragma unroll
        for (int n = 0; n < 16; ++n) {
            float cn = Cs[r][n];
            off0 += cn * ps[0][n];
            off1 += cn * ps[1][n];
        }
        float g0 = (b2f(yu.x) + sdo * off0 + b2f(xu.x) * d) * siluf(b2f(zu.x));
        float g1 = (b2f(yu.y) + sdo * off1 + b2f(xu.y) * d) * siluf(b2f(zu.y));
        g0r[r] = g0; g1r[r] = g1;
        float s = g0 * g0 + g1 * g1;
        #pragma unroll
        for (int o = 32; o > 0; o >>= 1) s += __shfl_down(s, o, 64);
        if (lane == 0) red[r][wv] = s;
    }
    __syncthreads();
    #pragma unroll
    for (int r = 0; r < 16; ++r) {
        const size_t grow = (size_t)(brow0 + r0 + r);
        float tot = 0.f;
        #pragma unroll
        for (int w2 = 0; w2 < 8; ++w2) tot += red[r][w2];
        float rstd = rsqrtf(tot * (1.f / (float)D_INNER) + 1e-5f);
        ushort2 o2;
        o2.x = f2b(g0r[r] * rstd * nw0);
        o2.y = f2b(g1r[r] * rstd * nw1);
        *(ushort2*)(yout + grow * D_INNER + ch0) = o2;
    }
}

extern "C" void kernel_launch(void* const* d_in, const int* in_sizes, int n_in,
                              void* d_out, int out_size, void* d_ws, size_t ws_size,
                              hipStream_t stream) {
    const float* u     = (const float*)d_in[0];
    const float* Win   = (const float*)d_in[1];
    const float* cw    = (const float*)d_in[2];
    const float* cb    = (const float*)d_in[3];
    const float* dtb   = (const float*)d_in[4];
    const float* Alog  = (const float*)d_in[5];
    const float* Dsk   = (const float*)d_in[6];
    const float* normw = (const float*)d_in[7];
    const float* Wout  = (const float*)d_in[8];
    float* out = (float*)d_out;

    float* ws = (float*)d_ws;
    unsigned short* zxb = (unsigned short*)ws;             // 8192*2176 bf16 = 8,912,896 f32
    float* dtsp   = ws + 8912896;                          // 524288
    float* csb    = dtsp + 524288;                         // 524288
    float* st     = csb + 524288;                          // 524288
    float* pst    = st + 524288;                           // 524288
    float* csum   = pst + 524288;                          // 2048
    unsigned short* ypre16 = (unsigned short*)(csum + 2048);              // 8192*1024 bf16
    unsigned short* xcb    = (unsigned short*)((float*)ypre16 + 4194304); // 8,650,752 bf16
    unsigned short* yn_bf  = (unsigned short*)((float*)xcb + 4325376);    // 8192*1024 bf16
    unsigned short* u_bf   = (unsigned short*)((float*)yn_bf + 2097152);  // 8192*512 bf16
    unsigned short* win_bf  = (unsigned short*)((float*)u_bf + 2097152);  // 2176*512 bf16
    unsigned short* wout_bf = (unsigned short*)((float*)win_bf + 557056); // 512*1024 bf16

    cast_all<<<2848, 256, 0, stream>>>(u, Win, Wout, u_bf, win_bf, wout_bf);

    gemm_in<<<2176, 256, 0, stream>>>(u_bf, win_bf, zxb, dtsp, dtb);

    conv_silu44<<<(ROWS / 4) * (CONV_DIM / 4) / 256, 256, 0, stream>>>(zxb, cw, cb, xcb);
    ssd_chunk<<<BATCH * NCHUNK * NHEADS, 256, 0, stream>>>(xcb, dtsp, Alog, ypre16, st, csb, csum);
    ssd_rec<<<BATCH * NHEADS, 256, 0, stream>>>(st, csum, pst);
    ssd_off_norm<<<512, 512, 0, stream>>>(xcb, zxb, ypre16, pst, csb, Dsk, normw, yn_bf);

    gemm_out<<<dim3(8, 64), 256, 0, stream>>>(yn_bf, wout_bf, out);
}